// Round 5
// baseline (181.187 us; speedup 1.0000x reference)
//
#include <hip/hip_runtime.h>
#include <stdint.h>

// Problem constants
#define B_   8
#define S_   2047
#define L_   2048      // S+1 (CLS prepended)
#define H_   256       // HIDDEN
#define NH_  8
#define HD_  32
#define V_   32001     // VOCAB+1

__device__ __forceinline__ float foldx(float a, int off) {
    return a + __shfl_xor(a, off, 64);
}
__device__ __forceinline__ float sel8(const float a[8], int j) {
    float v = a[0];
    v = (j == 1) ? a[1] : v;
    v = (j == 2) ? a[2] : v;
    v = (j == 3) ? a[3] : v;
    v = (j == 4) ? a[4] : v;
    v = (j == 5) ? a[5] : v;
    v = (j == 6) ? a[6] : v;
    v = (j == 7) ? a[7] : v;
    return v;
}

// ---------------------------------------------------------------------------
// K0 (grid 8, block per head n): y0 = emb[2]+pe[0]; q0[k] = wq[n,k,:]·y0;
// qk[n][h] = (sum_k q0[k]*wk[n,k,h]) / sqrt(32). Block n zeroes counters[n].
// ---------------------------------------------------------------------------
__global__ __launch_bounds__(256) void k0_prep(const float* __restrict__ emb,
                                               const float* __restrict__ wq,
                                               const float* __restrict__ wk,
                                               float* __restrict__ qk,
                                               float* __restrict__ y0,
                                               int* __restrict__ counters) {
    __shared__ float y0_l[H_];
    __shared__ float q0p[HD_][8];
    __shared__ float q0_l[HD_];
    int n = blockIdx.x, tid = threadIdx.x;
    if (tid == 0) counters[n] = 0;
    float v = emb[2 * H_ + tid] + ((tid & 1) ? 1.0f : 0.0f);  // pe[0]: sin0/cos0
    y0_l[tid] = v;
    if (n == 0) y0[tid] = v;
    __syncthreads();
    {   // q0 partials: thread = (k, part); part covers 32 h
        int k = tid >> 3, part = tid & 7;
        const float* w = wq + (n * HD_ + k) * H_ + part * 32;
        const float* yy = y0_l + part * 32;
        float acc = 0.f;
#pragma unroll
        for (int j = 0; j < 32; ++j) acc += w[j] * yy[j];
        q0p[k][part] = acc;
    }
    __syncthreads();
    if (tid < HD_) {
        float s = 0.f;
#pragma unroll
        for (int j = 0; j < 8; ++j) s += q0p[tid][j];
        q0_l[tid] = s;
    }
    __syncthreads();
    float acc = 0.f;
    for (int k = 0; k < HD_; ++k)
        acc += q0_l[k] * wk[(n * HD_ + k) * H_ + tid];
    qk[n * H_ + tid] = acc * 0.17677669529663687f;  // 1/sqrt(32)
}

// ---------------------------------------------------------------------------
// K13T fused (grid 256 = b*32+c, 64 t per block, wave owns 16 t):
// y in registers -> scores (17-shuffle fold) -> exp -> ybar partial (LDS
// reduce) -> wv-projection -> op_partial (1 KB/block) + esum_blk.
// Last block per b (device counter) reduces op/esum, applies wo + residuals,
// writes z[b]. Softmax needs no max-sub: |scores| < 1 by construction.
// ---------------------------------------------------------------------------
__global__ __launch_bounds__(256, 1) void k13_attn(const int* __restrict__ x,
                                                   const float* __restrict__ emb,
                                                   const float* __restrict__ qkw,
                                                   const float* __restrict__ wv,
                                                   const float* __restrict__ wo,
                                                   const float* __restrict__ y0g,
                                                   float* __restrict__ op_partial,
                                                   float* __restrict__ esum_blk,
                                                   float* __restrict__ z,
                                                   int* __restrict__ counters) {
    int bid = blockIdx.x;            // b*32 + c
    int b = bid >> 5, c = bid & 31;
    int tid = threadIdx.x, lane = tid & 63, w = tid >> 6;
    int t0 = c * 64 + w * 16;

    __shared__ float4 p_l4[64][2];                    // P[t_local][n]
    __shared__ __align__(16) float red[4][NH_ * H_];  // per-wave ybar partials
    __shared__ float es_l[4][NH_];
    __shared__ int is_last;
    __shared__ float inv_l[NH_];
    __shared__ float o_l[H_];

    float4 qr[NH_];
#pragma unroll
    for (int n = 0; n < NH_; ++n)
        qr[n] = *(const float4*)(qkw + n * H_ + lane * 4);

    // pe recurrence setup: lane covers h-pairs i0=lane*2, i1=lane*2+1
    const float cdiv = 0.07195578414202881f;          // ln(10000)/128
    float div0 = expf(-(float)(lane * 2) * cdiv);
    float div1 = expf(-(float)(lane * 2 + 1) * cdiv);
    float s0, c0, s1, c1, sd0, cd0, sd1, cd1;
    {
        float a0 = (float)t0 * div0, a1 = (float)t0 * div1;
        s0 = sinf(a0); c0 = cosf(a0); s1 = sinf(a1); c1 = cosf(a1);
        sd0 = sinf(div0); cd0 = cosf(div0);
        sd1 = sinf(div1); cd1 = cosf(div1);
    }

    float4 yreg[16];
    float es = 0.f;

#pragma unroll
    for (int i = 0; i < 16; ++i) {
        int t = t0 + i;
        int tok = (t == 0) ? 2 : x[b * S_ + t - 1];
        float4 ev = *(const float4*)(emb + (size_t)tok * H_ + lane * 4);
        float4 y4;
        y4.x = ev.x + s0; y4.y = ev.y + c0; y4.z = ev.z + s1; y4.w = ev.w + c1;
        yreg[i] = y4;
        // rotate pe by one t-step
        float ns0 = s0 * cd0 + c0 * sd0; c0 = c0 * cd0 - s0 * sd0; s0 = ns0;
        float ns1 = s1 * cd1 + c1 * sd1; c1 = c1 * cd1 - s1 * sd1; s1 = ns1;

        // scores: 8 dots, 17-shuffle fold-reduce (optimal for this shape)
        float a[NH_];
#pragma unroll
        for (int n = 0; n < NH_; ++n)
            a[n] = qr[n].x * y4.x + qr[n].y * y4.y + qr[n].z * y4.z + qr[n].w * y4.w;
        float m4[4];
#pragma unroll
        for (int k = 0; k < 4; ++k) {
            float lo = foldx(a[k], 32), hi = foldx(a[k + 4], 32);
            m4[k] = (lane & 32) ? hi : lo;
        }
        float m2[2];
#pragma unroll
        for (int k = 0; k < 2; ++k) {
            float lo = foldx(m4[k], 16), hi = foldx(m4[k + 2], 16);
            m2[k] = (lane & 16) ? hi : lo;
        }
        float lo = foldx(m2[0], 8), hi = foldx(m2[1], 8);
        float m1 = (lane & 8) ? hi : lo;
        m1 = foldx(m1, 4); m1 = foldx(m1, 2); m1 = foldx(m1, 1);
        float e = __expf(m1);      // no max-sub: |m1| < 1
        es += e;                   // row-sum partial (head = lane>>3)
        if ((lane & 7) == 0)
            ((float*)&p_l4[w * 16 + i][0])[lane >> 3] = e;
    }
    if ((lane & 7) == 0) es_l[w][lane >> 3] = es;

    // ybar partial over this wave's 16 t (y from registers, P via LDS bcast)
    float4 acc4[NH_];
#pragma unroll
    for (int n = 0; n < NH_; ++n) acc4[n] = make_float4(0.f, 0.f, 0.f, 0.f);
#pragma unroll
    for (int i = 0; i < 16; ++i) {
        float4 pA = p_l4[w * 16 + i][0];
        float4 pB = p_l4[w * 16 + i][1];
        float p[NH_] = {pA.x, pA.y, pA.z, pA.w, pB.x, pB.y, pB.z, pB.w};
        float4 y4 = yreg[i];
#pragma unroll
        for (int n = 0; n < NH_; ++n) {
            acc4[n].x += p[n] * y4.x;
            acc4[n].y += p[n] * y4.y;
            acc4[n].z += p[n] * y4.z;
            acc4[n].w += p[n] * y4.w;
        }
    }
#pragma unroll
    for (int n = 0; n < NH_; ++n)
        *(float4*)&red[w][n * H_ + lane * 4] = acc4[n];
    __syncthreads();
    // cross-wave reduce into red[0] (psum, n-major); each slot one thread
#pragma unroll
    for (int g = 0; g < 2; ++g) {
        int idx = tid * 8 + g * 4;
        float4 r0 = *(const float4*)&red[0][idx];
        float4 r1 = *(const float4*)&red[1][idx];
        float4 r2 = *(const float4*)&red[2][idx];
        float4 r3 = *(const float4*)&red[3][idx];
        float4 s;
        s.x = r0.x + r1.x + r2.x + r3.x;
        s.y = r0.y + r1.y + r2.y + r3.y;
        s.z = r0.z + r1.z + r2.z + r3.z;
        s.w = r0.w + r1.w + r2.w + r3.w;
        *(float4*)&red[0][idx] = s;
    }
    if (tid < NH_)
        esum_blk[bid * NH_ + tid] = es_l[0][tid] + es_l[1][tid] + es_l[2][tid] + es_l[3][tid];
    __syncthreads();
    // wv projection of the block's psum: op[j] = wv[j,:]·psum[n(j),:]
    {
        int n = tid >> 5;
        const float* wrow = wv + (size_t)tid * H_;
        const float* ps = &red[0][n * H_];
        float acc = 0.f;
#pragma unroll 16
        for (int h4 = 0; h4 < H_ / 4; ++h4) {
            float4 wv4 = *(const float4*)(wrow + h4 * 4);
            float4 p4 = *(const float4*)(ps + h4 * 4);
            acc += wv4.x * p4.x + wv4.y * p4.y + wv4.z * p4.z + wv4.w * p4.w;
        }
        op_partial[bid * H_ + tid] = acc;
    }

    // ---- last-block-per-b tail ----
    __threadfence();
    __syncthreads();
    if (tid == 0) is_last = (atomicAdd(&counters[b], 1) == 31);
    __syncthreads();
    if (!is_last) return;
    __threadfence();

    if (tid < NH_) {
        float s = 0.f;
#pragma unroll
        for (int cc = 0; cc < 32; ++cc) s += esum_blk[(b * 32 + cc) * NH_ + tid];
        inv_l[tid] = 1.0f / s;
    }
    __syncthreads();
    {
        float s = 0.f;
#pragma unroll
        for (int cc = 0; cc < 32; ++cc) s += op_partial[(b * 32 + cc) * H_ + tid];
        o_l[tid] = s * inv_l[tid >> 5];
    }
    __syncthreads();
    {
        const float* wrow = wo + (size_t)tid * H_;
        float s = 0.f;
#pragma unroll 16
        for (int j4 = 0; j4 < H_ / 4; ++j4) {
            float4 w4 = *(const float4*)(wrow + j4 * 4);
            s += w4.x * o_l[j4 * 4] + w4.y * o_l[j4 * 4 + 1]
               + w4.z * o_l[j4 * 4 + 2] + w4.w * o_l[j4 * 4 + 3];
        }
        z[b * H_ + tid] = s + 2.0f * y0g[tid];
    }
}

// ---------------------------------------------------------------------------
// K5 (grid 501): out[b,v] = z[b,:]·wu[v,:]. 16-lane groups own 16-h spans;
// 4 rows per pass per wave -> 8 shuffles/row.
// ---------------------------------------------------------------------------
__global__ __launch_bounds__(256) void k5_out(const float* __restrict__ z,
                                              const float* __restrict__ wu,
                                              float* __restrict__ out) {
    int tid = threadIdx.x, lane = tid & 63, w = tid >> 6;
    int m = lane & 15;
    int g = lane >> 4;
    int hb = m * 16;
    float zr[B_][16];
#pragma unroll
    for (int b = 0; b < B_; ++b)
#pragma unroll
        for (int jj = 0; jj < 4; ++jj)
            *(float4*)&zr[b][jj * 4] = *(const float4*)(z + b * H_ + hb + jj * 4);

    __shared__ float o_l[B_ * 65];
    int base = blockIdx.x * 64;
#pragma unroll
    for (int pass = 0; pass < 4; ++pass) {
        int rl = w * 16 + pass * 4 + g;
        int v = base + rl;
        int vc = (v < V_) ? v : (V_ - 1);
        const float* wr = wu + (size_t)vc * H_ + hb;
        float4 w0 = *(const float4*)(wr);
        float4 w1 = *(const float4*)(wr + 4);
        float4 w2 = *(const float4*)(wr + 8);
        float4 w3 = *(const float4*)(wr + 12);
        float acc[B_];
#pragma unroll
        for (int b = 0; b < B_; ++b) {
            acc[b] = zr[b][0] * w0.x + zr[b][1] * w0.y + zr[b][2] * w0.z + zr[b][3] * w0.w
                   + zr[b][4] * w1.x + zr[b][5] * w1.y + zr[b][6] * w1.z + zr[b][7] * w1.w
                   + zr[b][8] * w2.x + zr[b][9] * w2.y + zr[b][10] * w2.z + zr[b][11] * w2.w
                   + zr[b][12] * w3.x + zr[b][13] * w3.y + zr[b][14] * w3.z + zr[b][15] * w3.w;
        }
#pragma unroll
        for (int off = 1; off <= 8; off <<= 1) {
#pragma unroll
            for (int b = 0; b < B_; ++b) acc[b] += __shfl_xor(acc[b], off, 64);
        }
        if (m < B_) o_l[m * 65 + rl] = sel8(acc, m);
    }
    __syncthreads();
    for (int i = tid; i < B_ * 64; i += 256) {
        int b = i >> 6, vl = i & 63, v = base + vl;
        if (v < V_) out[b * V_ + v] = o_l[b * 65 + vl];
    }
}

// ---------------------------------------------------------------------------
extern "C" void kernel_launch(void* const* d_in, const int* in_sizes, int n_in,
                              void* d_out, int out_size, void* d_ws, size_t ws_size,
                              hipStream_t stream) {
    const int*   x   = (const int*)d_in[0];
    const float* emb = (const float*)d_in[1];
    const float* wq  = (const float*)d_in[2];
    const float* wk  = (const float*)d_in[3];
    const float* wv  = (const float*)d_in[4];
    const float* wo  = (const float*)d_in[5];
    const float* wu  = (const float*)d_in[6];
    float*       out = (float*)d_out;

    // ws layout (floats):
    // qk[2048] | y0[256] | z[2048] | esum_blk[2048] | op_partial[65536]
    // | counters[8]   (~285 KB)
    float* qk       = (float*)d_ws;
    float* y0       = qk + NH_ * H_;
    float* z        = y0 + H_;
    float* esum_blk = z + B_ * H_;
    float* op_part  = esum_blk + 256 * NH_;
    int*   counters = (int*)(op_part + 256 * H_);

    k0_prep <<<8,   256, 0, stream>>>(emb, wq, wk, qk, y0, counters);
    k13_attn<<<256, 256, 0, stream>>>(x, emb, qk, wv, wo, y0, op_part, esum_blk, z, counters);
    k5_out  <<<(V_ + 63) / 64, 256, 0, stream>>>(z, wu, out);
}